// Round 1
// baseline (489.212 us; speedup 1.0000x reference)
//
#include <hip/hip_runtime.h>
#include <hip/hip_bf16.h>
#include <stdint.h>

#define B_ 4
#define S_ 2048
#define D_ 1024
#define H_ 16
#define HD_ 64
#define TD_ 3072
#define SCALE_ 0.125f

typedef __attribute__((ext_vector_type(4))) float f32x4;
typedef __attribute__((ext_vector_type(8))) short s16x8;
typedef __attribute__((ext_vector_type(8))) unsigned short u16x8;
typedef __attribute__((ext_vector_type(4))) unsigned int u32x4;

typedef const __attribute__((address_space(1))) unsigned int* gas1p;
typedef __attribute__((address_space(3))) unsigned int* as3p;

__device__ inline void gload_lds16(const void* g, void* l) {
    __builtin_amdgcn_global_load_lds((gas1p)g, (as3p)l, 16, 0, 0);
}

__device__ inline unsigned short f2bf(float f) {
    unsigned u = __builtin_bit_cast(unsigned, f);
    u += 0x7FFFu + ((u >> 16) & 1u);
    return (unsigned short)(u >> 16);
}
__device__ inline float bf2f(unsigned short b) {
    unsigned u = ((unsigned)b) << 16;
    return __builtin_bit_cast(float, u);
}

// ---------------- dtype sniff ----------------
// If device buffers are bf16, the LOW ushort of each 32-bit word is a bf16
// sample of N(0,1): its exponent field (word bits 7..14) concentrates near
// 127. If fp32, bits 7..14 are random mantissa bits (uniform over 0..255).
__global__ void sniff_kernel(const unsigned* __restrict__ x, int* __restrict__ flag) {
    if (threadIdx.x == 0 && blockIdx.x == 0) {
        int cnt = 0;
        for (int i = 0; i < 512; i++) {
            unsigned e = (x[i] >> 7) & 0xFFu;
            if (e > 100u && e < 140u) cnt++;
        }
        *flag = (cnt > 300) ? 1 : 0;   // 1 = device buffers are bf16
    }
}

// ---------------- conversions ----------------
__global__ void cvt_bf16_kernel(const void* __restrict__ in, unsigned short* __restrict__ out,
                                long n8, const int* __restrict__ flag) {
    bool isbf = (*flag) != 0;
    long i = (long)blockIdx.x * blockDim.x + threadIdx.x;
    long stride = (long)gridDim.x * blockDim.x;
    for (; i < n8; i += stride) {
        if (isbf) {
            ((u32x4*)out)[i] = ((const u32x4*)in)[i];
        } else {
            const float* f = (const float*)in + i * 8;
            u16x8 r;
#pragma unroll
            for (int j = 0; j < 8; j++) r[j] = f2bf(f[j]);
            ((u16x8*)out)[i] = r;
        }
    }
}

// in: [R][C] (fp32 or bf16) -> out: [C][R] bf16
__global__ void tcvt_kernel(const void* __restrict__ in, unsigned short* __restrict__ out,
                            int R, int C, const int* __restrict__ flag) {
    bool isbf = (*flag) != 0;
    __shared__ unsigned short tile[32][33];
    int bx = blockIdx.x, by = blockIdx.y;
    int x = threadIdx.x, y0 = threadIdx.y;
    int c = bx * 32 + x;
    for (int yy = y0; yy < 32; yy += 8) {
        long r = by * 32 + yy;
        unsigned short v;
        if (isbf) v = ((const unsigned short*)in)[r * C + c];
        else      v = f2bf(((const float*)in)[r * C + c]);
        tile[yy][x] = v;
    }
    __syncthreads();
    for (int yy = y0; yy < 32; yy += 8) {
        out[(long)(bx * 32 + yy) * R + by * 32 + x] = tile[x][yy];
    }
}

__global__ void cvt_f32_kernel(const void* __restrict__ in, float* __restrict__ out,
                               int n, const int* __restrict__ flag) {
    bool isbf = (*flag) != 0;
    int i = blockIdx.x * blockDim.x + threadIdx.x;
    if (i < n) out[i] = isbf ? bf2f(((const unsigned short*)in)[i]) : ((const float*)in)[i];
}

// ---------------- GEMM: C[M,N] = A[M,K] x Bt[N,K]^T + bias ----------------
// m97 structure: 128x128 tile, BK=32, 4 waves (2x2), global_load_lds width 16.
__global__ __launch_bounds__(256)
void gemm_bt_kernel(const unsigned short* __restrict__ A,
                    const unsigned short* __restrict__ Bt,
                    const float* __restrict__ bias,
                    void* __restrict__ Cout,
                    int M, int N, int K, const int* __restrict__ flag) {
    __shared__ unsigned short As[128 * 32];
    __shared__ unsigned short Bs[128 * 32];
    int t = threadIdx.x;
    int lane = t & 63;
    int w = t >> 6, wr = w >> 1, wc = w & 1;
    int g = lane >> 4, x = lane & 15;
    long rm = (long)blockIdx.x * 128;
    long rn = (long)blockIdx.y * 128;
    const char* Ab = (const char*)(A + rm * K);
    const char* Bb = (const char*)(Bt + rn * K);
    int r0 = t >> 2;            // rows 0..63 for load0, +64 for load1
    int c0 = (t & 3) * 16;      // byte offset within 64B row
    long Kb = (long)K * 2;

    f32x4 acc[4][4] = {};

    for (int k0 = 0; k0 < K; k0 += 32) {
        __syncthreads();
        long kb = (long)k0 * 2;
        gload_lds16(Ab + (long)r0 * Kb + kb + c0,        (char*)As + t * 16);
        gload_lds16(Ab + (long)(r0 + 64) * Kb + kb + c0, (char*)As + t * 16 + 4096);
        gload_lds16(Bb + (long)r0 * Kb + kb + c0,        (char*)Bs + t * 16);
        gload_lds16(Bb + (long)(r0 + 64) * Kb + kb + c0, (char*)Bs + t * 16 + 4096);
        __syncthreads();

        s16x8 af[4], bfr[4];
#pragma unroll
        for (int m = 0; m < 4; m++) af[m]  = *(const s16x8*)&As[(wr * 64 + m * 16 + x) * 32 + g * 8];
#pragma unroll
        for (int n = 0; n < 4; n++) bfr[n] = *(const s16x8*)&Bs[(wc * 64 + n * 16 + x) * 32 + g * 8];
#pragma unroll
        for (int m = 0; m < 4; m++)
#pragma unroll
            for (int n = 0; n < 4; n++)
                acc[m][n] = __builtin_amdgcn_mfma_f32_16x16x32_bf16(af[m], bfr[n], acc[m][n], 0, 0, 0);
    }

    bool f32out = flag ? ((*flag) == 0) : false;
    float bv[4];
#pragma unroll
    for (int n = 0; n < 4; n++) bv[n] = bias[rn + wc * 64 + n * 16 + x];

#pragma unroll
    for (int m = 0; m < 4; m++) {
#pragma unroll
        for (int r = 0; r < 4; r++) {
            long row = rm + wr * 64 + m * 16 + g * 4 + r;
            if (f32out) {
                float* cp = (float*)Cout + row * N;
#pragma unroll
                for (int n = 0; n < 4; n++) cp[rn + wc * 64 + n * 16 + x] = acc[m][n][r] + bv[n];
            } else {
                unsigned short* cp = (unsigned short*)Cout + row * N;
#pragma unroll
                for (int n = 0; n < 4; n++) cp[rn + wc * 64 + n * 16 + x] = f2bf(acc[m][n][r] + bv[n]);
            }
        }
    }
}

// ---------------- flash attention (causal) ----------------
// Block: one (b,h), 64 Q rows. 4 waves x 16 rows. KT=64 key tiles.
// QKV layout: [B*S][3072] bf16, Q at +0, K at +1024, V at +2048 (+h*64).
__global__ __launch_bounds__(256)
void attn_kernel(const unsigned short* __restrict__ QKV, unsigned short* __restrict__ O) {
    __shared__ unsigned short Vt[64 * 64];     // [d][key], row=128B, XOR-swizzled 16B slots
    __shared__ unsigned short Pw[4][16 * 88];  // per-wave P [row][key], stride 88 elem (16B aligned)

    int t = threadIdx.x, lane = t & 63, w = t >> 6;
    int g = lane >> 4, x = lane & 15;
    int b = blockIdx.z, h = blockIdx.y;
    int q0 = blockIdx.x * 64;

    const unsigned short* base  = QKV + (long)b * S_ * TD_;
    const unsigned short* Kbase = base + D_;
    const unsigned short* Vbase = base + 2 * D_;

    // Q fragments (rows q0 + w*16 + x), hd halves
    long qrow = q0 + w * 16 + x;
    s16x8 qf0 = *(const s16x8*)&base[qrow * TD_ + h * HD_ + g * 8];
    s16x8 qf1 = *(const s16x8*)&base[qrow * TD_ + h * HD_ + 32 + g * 8];

    f32x4 acc[4] = {};
    float mrow[4], lrow[4];
#pragma unroll
    for (int r = 0; r < 4; r++) { mrow[r] = -__builtin_inff(); lrow[r] = 0.f; }

    int ntiles = blockIdx.x + 1;
    int rowq = q0 + w * 16 + g * 4;  // + r

    for (int kt = 0; kt < ntiles; kt++) {
        int ks = kt * 64;
        __syncthreads();   // protect Vt/Pw from previous iteration's readers

        // stage V tile transposed: thread t handles key=t>>2, d0=(t&3)*16
        {
            int key = t >> 2, d0 = (t & 3) * 16;
            const unsigned short* vr = Vbase + (long)(ks + key) * TD_ + h * HD_ + d0;
            u16x8 v0 = *(const u16x8*)vr;
            u16x8 v1 = *(const u16x8*)(vr + 8);
            int kk = key & 7, kb = key >> 3;
#pragma unroll
            for (int j = 0; j < 8; j++) {
                int d = d0 + j;
                Vt[d * 64 + ((kb ^ (d & 7)) << 3) + kk] = v0[j];
            }
#pragma unroll
            for (int j = 0; j < 8; j++) {
                int d = d0 + 8 + j;
                Vt[d * 64 + ((kb ^ (d & 7)) << 3) + kk] = v1[j];
            }
        }

        // QK^T: scores for 4 col-tiles of 16 keys
        f32x4 sf[4] = {};
#pragma unroll
        for (int ct = 0; ct < 4; ct++) {
            const unsigned short* kr = Kbase + (long)(ks + ct * 16 + x) * TD_ + h * HD_ + g * 8;
            s16x8 k0 = *(const s16x8*)kr;
            s16x8 k1 = *(const s16x8*)(kr + 32);
            sf[ct] = __builtin_amdgcn_mfma_f32_16x16x32_bf16(qf0, k0, sf[ct], 0, 0, 0);
            sf[ct] = __builtin_amdgcn_mfma_f32_16x16x32_bf16(qf1, k1, sf[ct], 0, 0, 0);
        }

        // scale + causal mask (only diagonal tile needs masking)
        if (kt == ntiles - 1) {
#pragma unroll
            for (int ct = 0; ct < 4; ct++)
#pragma unroll
                for (int r = 0; r < 4; r++) {
                    int colk = ks + ct * 16 + x;
                    float sv = sf[ct][r] * SCALE_;
                    if (colk > rowq + r) sv = -__builtin_inff();
                    sf[ct][r] = sv;
                }
        } else {
#pragma unroll
            for (int ct = 0; ct < 4; ct++)
#pragma unroll
                for (int r = 0; r < 4; r++) sf[ct][r] *= SCALE_;
        }

        // online softmax (rows live in 16-lane groups; 4-step xor reduce)
#pragma unroll
        for (int r = 0; r < 4; r++) {
            float tm = fmaxf(fmaxf(sf[0][r], sf[1][r]), fmaxf(sf[2][r], sf[3][r]));
            tm = fmaxf(tm, __shfl_xor(tm, 1));
            tm = fmaxf(tm, __shfl_xor(tm, 2));
            tm = fmaxf(tm, __shfl_xor(tm, 4));
            tm = fmaxf(tm, __shfl_xor(tm, 8));
            float mn = fmaxf(mrow[r], tm);
            float al = __expf(mrow[r] - mn);
            mrow[r] = mn;
            float ts = 0.f;
#pragma unroll
            for (int ct = 0; ct < 4; ct++) {
                float pv = __expf(sf[ct][r] - mn);
                sf[ct][r] = pv;
                ts += pv;
            }
            ts += __shfl_xor(ts, 1);
            ts += __shfl_xor(ts, 2);
            ts += __shfl_xor(ts, 4);
            ts += __shfl_xor(ts, 8);
            lrow[r] = lrow[r] * al + ts;
            acc[0][r] *= al; acc[1][r] *= al; acc[2][r] *= al; acc[3][r] *= al;
        }

        // write P (bf16) to per-wave LDS buffer
        unsigned short* pw = &Pw[w][0];
#pragma unroll
        for (int ct = 0; ct < 4; ct++)
#pragma unroll
            for (int r = 0; r < 4; r++)
                pw[(g * 4 + r) * 88 + ct * 16 + x] = f2bf(sf[ct][r]);

        __syncthreads();   // Vt staged + P visible

        // PV: A = P rows, B = Vt rows (output-col = hd)
        s16x8 pa0 = *(const s16x8*)&pw[x * 88 + g * 8];
        s16x8 pa1 = *(const s16x8*)&pw[x * 88 + 32 + g * 8];
#pragma unroll
        for (int c = 0; c < 4; c++) {
            int d = c * 16 + x;
            s16x8 vb0 = *(const s16x8*)&Vt[d * 64 + ((g ^ (x & 7)) << 3)];
            s16x8 vb1 = *(const s16x8*)&Vt[d * 64 + (((4 + g) ^ (x & 7)) << 3)];
            acc[c] = __builtin_amdgcn_mfma_f32_16x16x32_bf16(pa0, vb0, acc[c], 0, 0, 0);
            acc[c] = __builtin_amdgcn_mfma_f32_16x16x32_bf16(pa1, vb1, acc[c], 0, 0, 0);
        }
    }

    // normalize + store O [B*S][1024] bf16
#pragma unroll
    for (int r = 0; r < 4; r++) {
        float inv = 1.f / lrow[r];
        long orow = (long)b * S_ + q0 + w * 16 + g * 4 + r;
#pragma unroll
        for (int c = 0; c < 4; c++)
            O[orow * D_ + h * HD_ + c * 16 + x] = f2bf(acc[c][r] * inv);
    }
}

// ---------------- launcher ----------------
extern "C" void kernel_launch(void* const* d_in, const int* in_sizes, int n_in,
                              void* d_out, int out_size, void* d_ws, size_t ws_size,
                              hipStream_t stream) {
    char* ws = (char*)d_ws;
    int* flag            = (int*)ws;
    unsigned short* Xb   = (unsigned short*)(ws + 256);
    unsigned short* W1t  = Xb + 8192L * 1024;    // [3072][1024]
    unsigned short* QKV  = W1t + 3072L * 1024;   // [8192][3072]
    unsigned short* W2t  = QKV + 8192L * 3072;   // [1024][1024]
    unsigned short* Ob   = W2t + 1024L * 1024;   // [8192][1024]
    float* b1            = (float*)(Ob + 8192L * 1024);  // 3072
    float* b2            = b1 + 3072;                    // 1024

    sniff_kernel<<<1, 64, 0, stream>>>((const unsigned*)d_in[0], flag);

    cvt_bf16_kernel<<<4096, 256, 0, stream>>>(d_in[0], Xb, 8192L * 1024 / 8, flag);
    tcvt_kernel<<<dim3(96, 32), dim3(32, 8), 0, stream>>>(d_in[2], W1t, 1024, 3072, flag);
    tcvt_kernel<<<dim3(32, 32), dim3(32, 8), 0, stream>>>(d_in[4], W2t, 1024, 1024, flag);
    cvt_f32_kernel<<<12, 256, 0, stream>>>(d_in[3], b1, 3072, flag);
    cvt_f32_kernel<<<4, 256, 0, stream>>>(d_in[5], b2, 1024, flag);

    // QKV = X @ W_attn + b_attn  (bf16 out)
    gemm_bt_kernel<<<dim3(64, 24), 256, 0, stream>>>(Xb, W1t, b1, QKV, 8192, 3072, 1024, nullptr);

    // causal flash attention
    attn_kernel<<<dim3(32, 16, 4), 256, 0, stream>>>(QKV, Ob);

    // out = O @ W_proj + b_proj  (dtype per sniffed flag)
    gemm_bt_kernel<<<dim3(64, 8), 256, 0, stream>>>(Ob, W2t, b2, d_out, 8192, 1024, 1024, flag);
}

// Round 2
// 350.403 us; speedup vs baseline: 1.3961x; 1.3961x over previous
//
#include <hip/hip_runtime.h>
#include <hip/hip_bf16.h>
#include <stdint.h>

#define B_ 4
#define S_ 2048
#define D_ 1024
#define H_ 16
#define HD_ 64
#define TD_ 3072
#define SCALE_ 0.125f
#define KVB 64
#define QB 128

typedef __attribute__((ext_vector_type(4))) float f32x4;
typedef __attribute__((ext_vector_type(16))) float f32x16;
typedef __attribute__((ext_vector_type(8))) short s16x8;
typedef __attribute__((ext_vector_type(8))) unsigned short u16x8;
typedef __attribute__((ext_vector_type(4))) unsigned int u32x4;

typedef const __attribute__((address_space(1))) unsigned int* gas1p;
typedef __attribute__((address_space(3))) unsigned int* as3p;

__device__ inline void gload_lds16(const void* g, void* l) {
    __builtin_amdgcn_global_load_lds((gas1p)g, (as3p)l, 16, 0, 0);
}

__device__ inline unsigned short f2bf(float f) {
    unsigned u = __builtin_bit_cast(unsigned, f);
    u += 0x7FFFu + ((u >> 16) & 1u);
    return (unsigned short)(u >> 16);
}
__device__ inline float bf2f(unsigned short b) {
    unsigned u = ((unsigned)b) << 16;
    return __builtin_bit_cast(float, u);
}
__device__ inline unsigned cvtpk_bf16(float lo, float hi) {
    unsigned r;
    asm("v_cvt_pk_bf16_f32 %0, %1, %2" : "=v"(r) : "v"(lo), "v"(hi));
    return r;
}

// ---------------- dtype sniff ----------------
__global__ void sniff_kernel(const unsigned* __restrict__ x, int* __restrict__ flag) {
    if (threadIdx.x == 0 && blockIdx.x == 0) {
        int cnt = 0;
        for (int i = 0; i < 512; i++) {
            unsigned e = (x[i] >> 7) & 0xFFu;
            if (e > 100u && e < 140u) cnt++;
        }
        *flag = (cnt > 300) ? 1 : 0;   // 1 = device buffers are bf16
    }
}

// ---------------- conversions ----------------
__global__ void cvt_bf16_kernel(const void* __restrict__ in, unsigned short* __restrict__ out,
                                long n8, const int* __restrict__ flag) {
    bool isbf = (*flag) != 0;
    long i = (long)blockIdx.x * blockDim.x + threadIdx.x;
    long stride = (long)gridDim.x * blockDim.x;
    for (; i < n8; i += stride) {
        if (isbf) {
            ((u32x4*)out)[i] = ((const u32x4*)in)[i];
        } else {
            const float* f = (const float*)in + i * 8;
            u16x8 r;
#pragma unroll
            for (int j = 0; j < 8; j++) r[j] = f2bf(f[j]);
            ((u16x8*)out)[i] = r;
        }
    }
}

__global__ void tcvt_kernel(const void* __restrict__ in, unsigned short* __restrict__ out,
                            int R, int C, const int* __restrict__ flag) {
    bool isbf = (*flag) != 0;
    __shared__ unsigned short tile[32][33];
    int bx = blockIdx.x, by = blockIdx.y;
    int x = threadIdx.x, y0 = threadIdx.y;
    int c = bx * 32 + x;
    for (int yy = y0; yy < 32; yy += 8) {
        long r = by * 32 + yy;
        unsigned short v;
        if (isbf) v = ((const unsigned short*)in)[r * C + c];
        else      v = f2bf(((const float*)in)[r * C + c]);
        tile[yy][x] = v;
    }
    __syncthreads();
    for (int yy = y0; yy < 32; yy += 8) {
        out[(long)(bx * 32 + yy) * R + by * 32 + x] = tile[x][yy];
    }
}

__global__ void cvt_f32_kernel(const void* __restrict__ in, float* __restrict__ out,
                               int n, const int* __restrict__ flag) {
    bool isbf = (*flag) != 0;
    int i = blockIdx.x * blockDim.x + threadIdx.x;
    if (i < n) out[i] = isbf ? bf2f(((const unsigned short*)in)[i]) : ((const float*)in)[i];
}

// V global transpose: QKV [B*S][3072] (V at col 2048 + h*64) -> Vt [b*16+h][64][2048]
__global__ __launch_bounds__(512)
void vtrans_kernel(const unsigned short* __restrict__ QKV, unsigned short* __restrict__ Vt) {
    __shared__ unsigned short tile[64][72];
    int t = threadIdx.x;
    int st = blockIdx.x;        // s-tile 0..31
    int bh = blockIdx.y;        // b*16+h
    int b = bh >> 4, h = bh & 15;
    const unsigned short* src = QKV + (long)b * S_ * TD_ + 2 * D_ + h * HD_;
    int sr = t >> 3, d0 = (t & 7) * 8;
    u16x8 v = *(const u16x8*)(src + (long)(st * 64 + sr) * TD_ + d0);
    *(u16x8*)&tile[sr][d0] = v;
    __syncthreads();
    int dr = t >> 3, s0 = (t & 7) * 8;
    u16x8 o;
#pragma unroll
    for (int j = 0; j < 8; j++) o[j] = tile[s0 + j][dr];
    *(u16x8*)(Vt + ((long)bh * 64 + dr) * S_ + st * 64 + s0) = o;
}

// ---------------- GEMM: C[M,N] = A[M,K] x Bt[N,K]^T + bias ----------------
__global__ __launch_bounds__(256)
void gemm_bt_kernel(const unsigned short* __restrict__ A,
                    const unsigned short* __restrict__ Bt,
                    const float* __restrict__ bias,
                    void* __restrict__ Cout,
                    int M, int N, int K, const int* __restrict__ flag) {
    __shared__ unsigned short As[128 * 32];
    __shared__ unsigned short Bs[128 * 32];
    int t = threadIdx.x;
    int lane = t & 63;
    int w = t >> 6, wr = w >> 1, wc = w & 1;
    int g = lane >> 4, x = lane & 15;
    long rm = (long)blockIdx.x * 128;
    long rn = (long)blockIdx.y * 128;
    const char* Ab = (const char*)(A + rm * K);
    const char* Bb = (const char*)(Bt + rn * K);
    int r0 = t >> 2;
    int c0 = (t & 3) * 16;
    long Kb = (long)K * 2;

    f32x4 acc[4][4] = {};

    for (int k0 = 0; k0 < K; k0 += 32) {
        __syncthreads();
        long kb = (long)k0 * 2;
        gload_lds16(Ab + (long)r0 * Kb + kb + c0,        (char*)As + t * 16);
        gload_lds16(Ab + (long)(r0 + 64) * Kb + kb + c0, (char*)As + t * 16 + 4096);
        gload_lds16(Bb + (long)r0 * Kb + kb + c0,        (char*)Bs + t * 16);
        gload_lds16(Bb + (long)(r0 + 64) * Kb + kb + c0, (char*)Bs + t * 16 + 4096);
        __syncthreads();

        s16x8 af[4], bfr[4];
#pragma unroll
        for (int m = 0; m < 4; m++) af[m]  = *(const s16x8*)&As[(wr * 64 + m * 16 + x) * 32 + g * 8];
#pragma unroll
        for (int n = 0; n < 4; n++) bfr[n] = *(const s16x8*)&Bs[(wc * 64 + n * 16 + x) * 32 + g * 8];
#pragma unroll
        for (int m = 0; m < 4; m++)
#pragma unroll
            for (int n = 0; n < 4; n++)
                acc[m][n] = __builtin_amdgcn_mfma_f32_16x16x32_bf16(af[m], bfr[n], acc[m][n], 0, 0, 0);
    }

    bool f32out = flag ? ((*flag) == 0) : false;
    float bv[4];
#pragma unroll
    for (int n = 0; n < 4; n++) bv[n] = bias[rn + wc * 64 + n * 16 + x];

#pragma unroll
    for (int m = 0; m < 4; m++) {
#pragma unroll
        for (int r = 0; r < 4; r++) {
            long row = rm + wr * 64 + m * 16 + g * 4 + r;
            if (f32out) {
                float* cp = (float*)Cout + row * N;
#pragma unroll
                for (int n = 0; n < 4; n++) cp[rn + wc * 64 + n * 16 + x] = acc[m][n][r] + bv[n];
            } else {
                unsigned short* cp = (unsigned short*)Cout + row * N;
#pragma unroll
                for (int n = 0; n < 4; n++) cp[rn + wc * 64 + n * 16 + x] = f2bf(acc[m][n][r] + bv[n]);
            }
        }
    }
}

// ---------------- flash attention, 4-warp 32x32 swapped-QK^T ----------------
// Block: 128 q-rows (4 warps x 32), one (b,h). KVB=64 keys/tile.
// K staged [key][64d] XOR-swizzled; V staged from pre-transposed Vt_g as [d][64key]
// XOR-swizzled. Both via global_load_lds w=16 with pre-swizzled source columns.
// QK^T swapped: mfma(A=K, B=Q) -> S^T frag: lane owns q=lane&31, keys in regs.
__global__ __launch_bounds__(256)
void attn_kernel(const unsigned short* __restrict__ QKV,
                 const unsigned short* __restrict__ Vt_g,
                 unsigned short* __restrict__ O) {
    __shared__ unsigned short Ks[2][64 * 64];
    __shared__ unsigned short Vs[2][64 * 64];

    int t = threadIdx.x, lane = t & 63, w = t >> 6;
    int hi = lane >> 5, q32 = lane & 31;
    int b = blockIdx.z, h = blockIdx.y;
    int bxr = gridDim.x - 1 - blockIdx.x;      // longest blocks first (LPT)
    int q0 = bxr * QB;
    int q0w = q0 + w * 32;

    const unsigned short* base = QKV + (long)b * S_ * TD_;
    const unsigned short* Kb = base + D_ + h * HD_;
    const unsigned short* Vb = Vt_g + (long)(b * H_ + h) * HD_ * S_;

    // Q fragments (B-operand), SCALE folded in exactly (2^-3)
    s16x8 qf[4];
    {
        const unsigned short* qr = base + (long)(q0w + q32) * TD_ + h * HD_;
#pragma unroll
        for (int ds = 0; ds < 4; ds++) {
            u16x8 qraw = *(const u16x8*)(qr + ds * 16 + hi * 8);
            u16x8 qs;
#pragma unroll
            for (int j = 0; j < 8; j++) qs[j] = f2bf(bf2f(qraw[j]) * SCALE_);
            qf[ds] = __builtin_bit_cast(s16x8, qs);
        }
    }

    f32x16 acc0 = {}, acc1 = {};
    float rmax = -__builtin_inff(), denom = 0.f;

    int nt = (q0 + QB) / KVB;       // 2*bxr + 2
    int wlimit = q0w + 31;
    int qg = q0w + q32;

    // staging geometry: 2 chunks of 32 rows each for K and V
    int srow = t >> 3;                                  // 0..31
    int scol = (((t & 7) ^ (srow & 7)) << 3);           // pre-swizzled source col (elems)

#define STAGE(bi, kt_)                                                            \
    {                                                                             \
        int ks_ = (kt_) * KVB;                                                    \
        gload_lds16(Kb + (long)(ks_ + srow) * TD_ + scol,      (char*)Ks[bi] + t * 16);          \
        gload_lds16(Kb + (long)(ks_ + 32 + srow) * TD_ + scol, (char*)Ks[bi] + 4096 + t * 16);   \
        gload_lds16(Vb + (long)srow * S_ + ks_ + scol,         (char*)Vs[bi] + t * 16);          \
        gload_lds16(Vb + (long)(32 + srow) * S_ + ks_ + scol,  (char*)Vs[bi] + 4096 + t * 16);   \
    }

    STAGE(0, 0);
    __syncthreads();

    for (int kt = 0; kt < nt; kt++) {
        int bi = kt & 1;
        int ks = kt * KVB;
        if (kt + 1 < nt) STAGE(bi ^ 1, kt + 1);

        if (ks <= wlimit) {
            const char* KsB = (const char*)Ks[bi];
            const char* VsB = (const char*)Vs[bi];

            // ---- QK^T (swapped): sf[key-in-regs][q=lane&31] ----
            f32x16 sf0 = {}, sf1 = {};
#pragma unroll
            for (int ds = 0; ds < 4; ds++) {
                int krow0 = q32;        // keys 0..31
                int krow1 = 32 + q32;   // keys 32..63
                s16x8 kf0 = *(const s16x8*)(KsB + krow0 * 128 + (((ds * 2 + hi) ^ (krow0 & 7)) << 4));
                s16x8 kf1 = *(const s16x8*)(KsB + krow1 * 128 + (((ds * 2 + hi) ^ (krow1 & 7)) << 4));
                sf0 = __builtin_amdgcn_mfma_f32_32x32x16_bf16(kf0, qf[ds], sf0, 0, 0, 0);
                sf1 = __builtin_amdgcn_mfma_f32_32x32x16_bf16(kf1, qf[ds], sf1, 0, 0, 0);
            }

            // ---- causal mask (diagonal-crossing tiles only) ----
            if (ks + 63 > q0w) {
#pragma unroll
                for (int r = 0; r < 16; r++) {
                    int koff = (r & 3) + 8 * (r >> 2) + 4 * hi;
                    if (ks + koff > qg)      sf0[r] = -__builtin_inff();
                    if (ks + 32 + koff > qg) sf1[r] = -__builtin_inff();
                }
            }

            // ---- online softmax, fully in-register (q = lane&31) ----
            float tm = -__builtin_inff();
#pragma unroll
            for (int r = 0; r < 16; r++) tm = fmaxf(tm, fmaxf(sf0[r], sf1[r]));
            tm = fmaxf(tm, __shfl_xor(tm, 32));

            if (!__all(tm <= rmax + 8.0f)) {        // defer-max (T13)
                float mn = fmaxf(rmax, tm);
                float alpha = __expf(rmax - mn);
                rmax = mn;
                denom *= alpha;
#pragma unroll
                for (int r = 0; r < 16; r++) {
                    float ar = __shfl(alpha, (r & 3) + 8 * (r >> 2) + 4 * hi);
                    acc0[r] *= ar;
                    acc1[r] *= ar;
                }
            }

            float ts = 0.f;
#pragma unroll
            for (int r = 0; r < 16; r++) {
                sf0[r] = __expf(sf0[r] - rmax); ts += sf0[r];
                sf1[r] = __expf(sf1[r] - rmax); ts += sf1[r];
            }
            ts += __shfl_xor(ts, 32);
            denom += ts;

            // ---- PV: A-frag from sf via cvt_pk + permlane32_swap (T12) ----
#pragma unroll
            for (int kst = 0; kst < 4; kst++) {
                unsigned w00, w01, w10, w11;
                if (kst == 0) { w00=cvtpk_bf16(sf0[0],sf0[1]);  w01=cvtpk_bf16(sf0[2],sf0[3]);
                                w10=cvtpk_bf16(sf0[4],sf0[5]);  w11=cvtpk_bf16(sf0[6],sf0[7]); }
                else if (kst == 1) { w00=cvtpk_bf16(sf0[8],sf0[9]);   w01=cvtpk_bf16(sf0[10],sf0[11]);
                                     w10=cvtpk_bf16(sf0[12],sf0[13]); w11=cvtpk_bf16(sf0[14],sf0[15]); }
                else if (kst == 2) { w00=cvtpk_bf16(sf1[0],sf1[1]);  w01=cvtpk_bf16(sf1[2],sf1[3]);
                                     w10=cvtpk_bf16(sf1[4],sf1[5]);  w11=cvtpk_bf16(sf1[6],sf1[7]); }
                else { w00=cvtpk_bf16(sf1[8],sf1[9]);   w01=cvtpk_bf16(sf1[10],sf1[11]);
                       w10=cvtpk_bf16(sf1[12],sf1[13]); w11=cvtpk_bf16(sf1[14],sf1[15]); }
                auto sA = __builtin_amdgcn_permlane32_swap(w00, w10, false, false);
                auto sB = __builtin_amdgcn_permlane32_swap(w01, w11, false, false);
                union { unsigned u[4]; s16x8 v; } pa;
                pa.u[0] = sA[0]; pa.u[1] = sB[0]; pa.u[2] = sA[1]; pa.u[3] = sB[1];

                int d0 = q32;
                int d1 = 32 + q32;
                s16x8 vf0 = *(const s16x8*)(VsB + d0 * 128 + (((kst * 2 + hi) ^ (d0 & 7)) << 4));
                s16x8 vf1 = *(const s16x8*)(VsB + d1 * 128 + (((kst * 2 + hi) ^ (d1 & 7)) << 4));
                acc0 = __builtin_amdgcn_mfma_f32_32x32x16_bf16(pa.v, vf0, acc0, 0, 0, 0);
                acc1 = __builtin_amdgcn_mfma_f32_32x32x16_bf16(pa.v, vf1, acc1, 0, 0, 0);
            }
        }
        __syncthreads();
    }

    // ---- normalize + store ----
    float inv = 1.0f / denom;
#pragma unroll
    for (int r = 0; r < 16; r++) {
        float ir = __shfl(inv, (r & 3) + 8 * (r >> 2) + 4 * hi);
        long row = (long)b * S_ + q0w + (r & 3) + 8 * (r >> 2) + 4 * hi;
        O[row * D_ + h * HD_ + q32]      = f2bf(acc0[r] * ir);
        O[row * D_ + h * HD_ + 32 + q32] = f2bf(acc1[r] * ir);
    }
}

// ---------------- launcher ----------------
extern "C" void kernel_launch(void* const* d_in, const int* in_sizes, int n_in,
                              void* d_out, int out_size, void* d_ws, size_t ws_size,
                              hipStream_t stream) {
    char* ws = (char*)d_ws;
    int* flag            = (int*)ws;
    unsigned short* Xb   = (unsigned short*)(ws + 256);
    unsigned short* W1t  = Xb + 8192L * 1024;    // [3072][1024]
    unsigned short* QKV  = W1t + 3072L * 1024;   // [8192][3072]
    unsigned short* W2t  = QKV + 8192L * 3072;   // [1024][1024]
    unsigned short* Ob   = W2t + 1024L * 1024;   // [8192][1024]
    unsigned short* Vt_g = Ob + 8192L * 1024;    // [64 bh][64 d][2048 s]
    float* b1            = (float*)(Vt_g + 64L * 64 * 2048);  // 3072
    float* b2            = b1 + 3072;                         // 1024

    sniff_kernel<<<1, 64, 0, stream>>>((const unsigned*)d_in[0], flag);

    cvt_bf16_kernel<<<4096, 256, 0, stream>>>(d_in[0], Xb, 8192L * 1024 / 8, flag);
    tcvt_kernel<<<dim3(96, 32), dim3(32, 8), 0, stream>>>(d_in[2], W1t, 1024, 3072, flag);
    tcvt_kernel<<<dim3(32, 32), dim3(32, 8), 0, stream>>>(d_in[4], W2t, 1024, 1024, flag);
    cvt_f32_kernel<<<12, 256, 0, stream>>>(d_in[3], b1, 3072, flag);
    cvt_f32_kernel<<<4, 256, 0, stream>>>(d_in[5], b2, 1024, flag);

    // QKV = X @ W_attn + b_attn  (bf16 out)
    gemm_bt_kernel<<<dim3(64, 24), 256, 0, stream>>>(Xb, W1t, b1, QKV, 8192, 3072, 1024, nullptr);

    // V -> Vt_g [bh][d][s]
    vtrans_kernel<<<dim3(32, 64), 512, 0, stream>>>(QKV, Vt_g);

    // causal flash attention
    attn_kernel<<<dim3(16, 16, 4), 256, 0, stream>>>(QKV, Vt_g, Ob);

    // out = O @ W_proj + b_proj  (dtype per sniffed flag)
    gemm_bt_kernel<<<dim3(64, 8), 256, 0, stream>>>(Ob, W2t, b2, d_out, 8192, 1024, 1024, flag);
}

// Round 5
// 309.370 us; speedup vs baseline: 1.5813x; 1.1326x over previous
//
#include <hip/hip_runtime.h>
#include <hip/hip_bf16.h>
#include <stdint.h>

#define B_ 4
#define S_ 2048
#define D_ 1024
#define H_ 16
#define HD_ 64
#define TD_ 3072
#define SCALE_ 0.125f
// SCALE * log2(e): scores computed in log2 domain, exp2 replaces exp
#define SC2_ 0.18033688011112042f
#define KVB 64
#define QB 128

typedef __attribute__((ext_vector_type(4))) float f32x4;
typedef __attribute__((ext_vector_type(16))) float f32x16;
typedef __attribute__((ext_vector_type(8))) short s16x8;
typedef __attribute__((ext_vector_type(8))) unsigned short u16x8;
typedef __attribute__((ext_vector_type(4))) unsigned int u32x4;

typedef const __attribute__((address_space(1))) unsigned int* gas1p;
typedef __attribute__((address_space(3))) unsigned int* as3p;

__device__ inline void gload_lds16(const void* g, void* l) {
    __builtin_amdgcn_global_load_lds((gas1p)g, (as3p)l, 16, 0, 0);
}

__device__ inline unsigned short f2bf(float f) {
    unsigned u = __builtin_bit_cast(unsigned, f);
    u += 0x7FFFu + ((u >> 16) & 1u);
    return (unsigned short)(u >> 16);
}
__device__ inline float bf2f(unsigned short b) {
    unsigned u = ((unsigned)b) << 16;
    return __builtin_bit_cast(float, u);
}
__device__ inline unsigned cvtpk_bf16(float lo, float hi) {
    unsigned r;
    asm("v_cvt_pk_bf16_f32 %0, %1, %2" : "=v"(r) : "v"(lo), "v"(hi));
    return r;
}

// ---------------- dtype sniff (wave-parallel) ----------------
__global__ void sniff_kernel(const unsigned* __restrict__ x, int* __restrict__ flag) {
    int lane = threadIdx.x;     // 64 threads
    int cnt = 0;
#pragma unroll
    for (int i = 0; i < 8; i++) {
        unsigned e = (x[lane * 8 + i] >> 7) & 0xFFu;
        cnt += (e > 100u && e < 140u) ? 1 : 0;
    }
    cnt += __shfl_xor(cnt, 1);
    cnt += __shfl_xor(cnt, 2);
    cnt += __shfl_xor(cnt, 4);
    cnt += __shfl_xor(cnt, 8);
    cnt += __shfl_xor(cnt, 16);
    cnt += __shfl_xor(cnt, 32);
    if (lane == 0) *flag = (cnt > 300) ? 1 : 0;   // 1 = device buffers are bf16
}

// ---------------- conversions ----------------
__global__ void cvt_bf16_kernel(const void* __restrict__ in, unsigned short* __restrict__ out,
                                long n8, const int* __restrict__ flag) {
    bool isbf = (*flag) != 0;
    long i = (long)blockIdx.x * blockDim.x + threadIdx.x;
    long stride = (long)gridDim.x * blockDim.x;
    for (; i < n8; i += stride) {
        if (isbf) {
            ((u32x4*)out)[i] = ((const u32x4*)in)[i];
        } else {
            const float* f = (const float*)in + i * 8;
            u16x8 r;
#pragma unroll
            for (int j = 0; j < 8; j++) r[j] = f2bf(f[j]);
            ((u16x8*)out)[i] = r;
        }
    }
}

__global__ void tcvt_kernel(const void* __restrict__ in, unsigned short* __restrict__ out,
                            int R, int C, const int* __restrict__ flag) {
    bool isbf = (*flag) != 0;
    __shared__ unsigned short tile[32][33];
    int bx = blockIdx.x, by = blockIdx.y;
    int x = threadIdx.x, y0 = threadIdx.y;
    int c = bx * 32 + x;
    for (int yy = y0; yy < 32; yy += 8) {
        long r = by * 32 + yy;
        unsigned short v;
        if (isbf) v = ((const unsigned short*)in)[r * C + c];
        else      v = f2bf(((const float*)in)[r * C + c]);
        tile[yy][x] = v;
    }
    __syncthreads();
    for (int yy = y0; yy < 32; yy += 8) {
        out[(long)(bx * 32 + yy) * R + by * 32 + x] = tile[x][yy];
    }
}

__global__ void cvt_f32_kernel(const void* __restrict__ in, float* __restrict__ out,
                               int n, const int* __restrict__ flag) {
    bool isbf = (*flag) != 0;
    int i = blockIdx.x * blockDim.x + threadIdx.x;
    if (i < n) out[i] = isbf ? bf2f(((const unsigned short*)in)[i]) : ((const float*)in)[i];
}

// V global transpose: QKV [B*S][3072] (V at col 2048 + h*64) -> Vt [b*16+h][64][2048]
__global__ __launch_bounds__(512)
void vtrans_kernel(const unsigned short* __restrict__ QKV, unsigned short* __restrict__ Vt) {
    __shared__ unsigned short tile[64][72];
    int t = threadIdx.x;
    int st = blockIdx.x;        // s-tile 0..31
    int bh = blockIdx.y;        // b*16+h
    int b = bh >> 4, h = bh & 15;
    const unsigned short* src = QKV + (long)b * S_ * TD_ + 2 * D_ + h * HD_;
    int sr = t >> 3, d0 = (t & 7) * 8;
    u16x8 v = *(const u16x8*)(src + (long)(st * 64 + sr) * TD_ + d0);
    *(u16x8*)&tile[sr][d0] = v;
    __syncthreads();
    int dr = t >> 3, s0 = (t & 7) * 8;
    u16x8 o;
#pragma unroll
    for (int j = 0; j < 8; j++) o[j] = tile[s0 + j][dr];
    *(u16x8*)(Vt + ((long)bh * 64 + dr) * S_ + st * 64 + s0) = o;
}

// ---------------- GEMM: C[M,N] = A[M,K] x Bt[N,K]^T + bias ----------------
// m97 structure + T1 XCD-bijective block swizzle (bx-major chunks per XCD:
// each XCD owns a contiguous strip of M-tiles -> A panels stay L2-resident).
__global__ __launch_bounds__(256)
void gemm_bt_kernel(const unsigned short* __restrict__ A,
                    const unsigned short* __restrict__ Bt,
                    const float* __restrict__ bias,
                    void* __restrict__ Cout,
                    int M, int N, int K, const int* __restrict__ flag) {
    __shared__ unsigned short As[128 * 32];
    __shared__ unsigned short Bs[128 * 32];
    int t = threadIdx.x;
    int lane = t & 63;
    int w = t >> 6, wr = w >> 1, wc = w & 1;
    int g = lane >> 4, x = lane & 15;

    // T1: XCD-bijective remap (nwg % 8 == 0 for all our launches)
    int nbx = gridDim.x, nby = gridDim.y;
    int nwg = nbx * nby;
    int orig = blockIdx.x + nbx * blockIdx.y;
    int per = nwg >> 3;
    int idx = (orig & 7) * per + (orig >> 3);
    int bx = idx / nby;
    int by = idx - bx * nby;

    long rm = (long)bx * 128;
    long rn = (long)by * 128;
    const char* Ab = (const char*)(A + rm * K);
    const char* Bb = (const char*)(Bt + rn * K);
    int r0 = t >> 2;
    int c0 = (t & 3) * 16;
    long Kb = (long)K * 2;

    f32x4 acc[4][4] = {};

    for (int k0 = 0; k0 < K; k0 += 32) {
        __syncthreads();
        long kb = (long)k0 * 2;
        gload_lds16(Ab + (long)r0 * Kb + kb + c0,        (char*)As + t * 16);
        gload_lds16(Ab + (long)(r0 + 64) * Kb + kb + c0, (char*)As + t * 16 + 4096);
        gload_lds16(Bb + (long)r0 * Kb + kb + c0,        (char*)Bs + t * 16);
        gload_lds16(Bb + (long)(r0 + 64) * Kb + kb + c0, (char*)Bs + t * 16 + 4096);
        __syncthreads();

        s16x8 af[4], bfr[4];
#pragma unroll
        for (int m = 0; m < 4; m++) af[m]  = *(const s16x8*)&As[(wr * 64 + m * 16 + x) * 32 + g * 8];
#pragma unroll
        for (int n = 0; n < 4; n++) bfr[n] = *(const s16x8*)&Bs[(wc * 64 + n * 16 + x) * 32 + g * 8];
#pragma unroll
        for (int m = 0; m < 4; m++)
#pragma unroll
            for (int n = 0; n < 4; n++)
                acc[m][n] = __builtin_amdgcn_mfma_f32_16x16x32_bf16(af[m], bfr[n], acc[m][n], 0, 0, 0);
    }

    bool f32out = flag ? ((*flag) == 0) : false;
    float bv[4];
#pragma unroll
    for (int n = 0; n < 4; n++) bv[n] = bias[rn + wc * 64 + n * 16 + x];

#pragma unroll
    for (int m = 0; m < 4; m++) {
#pragma unroll
        for (int r = 0; r < 4; r++) {
            long row = rm + wr * 64 + m * 16 + g * 4 + r;
            if (f32out) {
                float* cp = (float*)Cout + row * N;
#pragma unroll
                for (int n = 0; n < 4; n++) cp[rn + wc * 64 + n * 16 + x] = acc[m][n][r] + bv[n];
            } else {
                unsigned short* cp = (unsigned short*)Cout + row * N;
#pragma unroll
                for (int n = 0; n < 4; n++) cp[rn + wc * 64 + n * 16 + x] = f2bf(acc[m][n][r] + bv[n]);
            }
        }
    }
}

// ---------------- flash attention, paired causal blocks ----------------
// Grid (8,16,4): block pair i handles q-tiles i and 15-i -> uniform 34 kv-tiles.
// 4 warps x 32 q-rows. Swapped QK^T (mfma(K,Q)), in-register softmax in exp2
// domain, cvt_pk+permlane32 P-frag build, K/V staged via global_load_lds w=16
// with XOR-pre-swizzled source columns.
__global__ __launch_bounds__(256)
void attn_kernel(const unsigned short* __restrict__ QKV,
                 const unsigned short* __restrict__ Vt_g,
                 unsigned short* __restrict__ O) {
    __shared__ unsigned short Ks[2][64 * 64];
    __shared__ unsigned short Vs[2][64 * 64];

    int t = threadIdx.x, lane = t & 63, w = t >> 6;
    int hi = lane >> 5, q32 = lane & 31;
    int b = blockIdx.z, h = blockIdx.y;
    int pair = blockIdx.x;

    const unsigned short* base = QKV + (long)b * S_ * TD_;
    const unsigned short* Kb = base + D_ + h * HD_;
    const unsigned short* Vb = Vt_g + (long)(b * H_ + h) * HD_ * S_;

    // staging geometry: 2 chunks of 32 rows each for K and V
    int srow = t >> 3;                                  // 0..31
    int scol = (((t & 7) ^ (srow & 7)) << 3);           // pre-swizzled source col (elems)

#define STAGE(bi, kt_)                                                            \
    {                                                                             \
        int ks_ = (kt_) * KVB;                                                    \
        gload_lds16(Kb + (long)(ks_ + srow) * TD_ + scol,      (char*)Ks[bi] + t * 16);          \
        gload_lds16(Kb + (long)(ks_ + 32 + srow) * TD_ + scol, (char*)Ks[bi] + 4096 + t * 16);   \
        gload_lds16(Vb + (long)srow * S_ + ks_ + scol,         (char*)Vs[bi] + t * 16);          \
        gload_lds16(Vb + (long)(32 + srow) * S_ + ks_ + scol,  (char*)Vs[bi] + 4096 + t * 16);   \
    }

    for (int ph = 0; ph < 2; ph++) {
        int qt = ph ? (15 - pair) : pair;
        int q0 = qt * QB;
        int q0w = q0 + w * 32;
        int nt = 2 * qt + 2;
        int wlimit = q0w + 31;
        int qg = q0w + q32;

        // Q fragments (B-operand), SCALE*log2e folded in
        s16x8 qf[4];
        {
            const unsigned short* qr = base + (long)(q0w + q32) * TD_ + h * HD_;
#pragma unroll
            for (int ds = 0; ds < 4; ds++) {
                u16x8 qraw = *(const u16x8*)(qr + ds * 16 + hi * 8);
                u16x8 qs;
#pragma unroll
                for (int j = 0; j < 8; j++) qs[j] = f2bf(bf2f(qraw[j]) * SC2_);
                qf[ds] = __builtin_bit_cast(s16x8, qs);
            }
        }

        f32x16 acc0 = {}, acc1 = {};
        float rmax = -__builtin_inff(), denom = 0.f;

        STAGE(0, 0);
        __syncthreads();

        for (int kt = 0; kt < nt; kt++) {
            int bi = kt & 1;
            int ks = kt * KVB;
            if (kt + 1 < nt) STAGE(bi ^ 1, kt + 1);

            if (ks <= wlimit) {
                const char* KsB = (const char*)Ks[bi];
                const char* VsB = (const char*)Vs[bi];

                // ---- QK^T (swapped): sf[key-in-regs][q=lane&31], log2 domain ----
                f32x16 sf0 = {}, sf1 = {};
                __builtin_amdgcn_s_setprio(1);
#pragma unroll
                for (int ds = 0; ds < 4; ds++) {
                    int krow0 = q32;
                    int krow1 = 32 + q32;
                    s16x8 kf0 = *(const s16x8*)(KsB + krow0 * 128 + (((ds * 2 + hi) ^ (krow0 & 7)) << 4));
                    s16x8 kf1 = *(const s16x8*)(KsB + krow1 * 128 + (((ds * 2 + hi) ^ (krow1 & 7)) << 4));
                    sf0 = __builtin_amdgcn_mfma_f32_32x32x16_bf16(kf0, qf[ds], sf0, 0, 0, 0);
                    sf1 = __builtin_amdgcn_mfma_f32_32x32x16_bf16(kf1, qf[ds], sf1, 0, 0, 0);
                }
                __builtin_amdgcn_s_setprio(0);

                // ---- causal mask (diagonal-crossing tiles only) ----
                if (ks + 63 > q0w) {
#pragma unroll
                    for (int r = 0; r < 16; r++) {
                        int koff = (r & 3) + 8 * (r >> 2) + 4 * hi;
                        if (ks + koff > qg)      sf0[r] = -__builtin_inff();
                        if (ks + 32 + koff > qg) sf1[r] = -__builtin_inff();
                    }
                }

                // ---- online softmax, in-register, exp2 domain ----
                float tm = -__builtin_inff();
#pragma unroll
                for (int r = 0; r < 16; r++) tm = fmaxf(tm, fmaxf(sf0[r], sf1[r]));
                tm = fmaxf(tm, __shfl_xor(tm, 32));

                if (!__all(tm <= rmax + 8.0f)) {        // defer-max (T13)
                    float mn = fmaxf(rmax, tm);
                    float alpha = exp2f(rmax - mn);
                    rmax = mn;
                    denom *= alpha;
#pragma unroll
                    for (int r = 0; r < 16; r++) {
                        float ar = __shfl(alpha, (r & 3) + 8 * (r >> 2) + 4 * hi);
                        acc0[r] *= ar;
                        acc1[r] *= ar;
                    }
                }

                float ts = 0.f;
#pragma unroll
                for (int r = 0; r < 16; r++) {
                    sf0[r] = exp2f(sf0[r] - rmax); ts += sf0[r];
                    sf1[r] = exp2f(sf1[r] - rmax); ts += sf1[r];
                }
                ts += __shfl_xor(ts, 32);
                denom += ts;

                // ---- PV: A-frag from sf via cvt_pk + permlane32_swap (T12) ----
                __builtin_amdgcn_s_setprio(1);
#pragma unroll
                for (int kst = 0; kst < 4; kst++) {
                    unsigned w00, w01, w10, w11;
                    if (kst == 0) { w00=cvtpk_bf16(sf0[0],sf0[1]);  w01=cvtpk_bf16(sf0[2],sf0[3]);
                                    w10=cvtpk_bf16(sf0[4],sf0[5]);  w11=cvtpk_bf16(sf0[6],sf0[7]); }
                    else if (kst == 1) { w00=cvtpk_bf16(sf0[8],sf0[9]);   w01=cvtpk_bf16(sf0[10],sf0[11]);
                                         w10=cvtpk_bf16(sf0[12],sf0[13]); w11=cvtpk_bf16(sf0[14],sf0[15]); }
                    else if (kst == 2) { w00=cvtpk_bf16(sf1[0],sf1[1]);  w01=cvtpk_bf16(sf1[2],sf1[3]);
                                         w10=cvtpk_bf16(sf1[4],sf1[5]);  w11=cvtpk_bf16(sf1[6],sf1[7]); }
                    else { w00=cvtpk_bf16(sf1[8],sf1[9]);   w01=cvtpk_bf16(sf1[10],sf1[11]);
                           w10=cvtpk_bf16(sf1[12],sf1[13]); w11=cvtpk_bf16(sf1[14],sf1[15]); }
                    auto sA = __builtin_amdgcn_permlane32_swap(w00, w10, false, false);
                    auto sB = __builtin_amdgcn_permlane32_swap(w01, w11, false, false);
                    union { unsigned u[4]; s16x8 v; } pa;
                    pa.u[0] = sA[0]; pa.u[1] = sB[0]; pa.u[2] = sA[1]; pa.u[3] = sB[1];

                    int d0 = q32;
                    int d1 = 32 + q32;
                    s16x8 vf0 = *(const s16x8*)(VsB + d0 * 128 + (((kst * 2 + hi) ^ (d0 & 7)) << 4));
                    s16x8 vf1 = *(const s16x8*)(VsB + d1 * 128 + (((kst * 2 + hi) ^ (d1 & 7)) << 4));
                    acc0 = __builtin_amdgcn_mfma_f32_32x32x16_bf16(pa.v, vf0, acc0, 0, 0, 0);
                    acc1 = __builtin_amdgcn_mfma_f32_32x32x16_bf16(pa.v, vf1, acc1, 0, 0, 0);
                }
                __builtin_amdgcn_s_setprio(0);
            }
            __syncthreads();
        }

        // ---- normalize + store ----
        float inv = 1.0f / denom;
#pragma unroll
        for (int r = 0; r < 16; r++) {
            float ir = __shfl(inv, (r & 3) + 8 * (r >> 2) + 4 * hi);
            long row = (long)b * S_ + q0w + (r & 3) + 8 * (r >> 2) + 4 * hi;
            O[row * D_ + h * HD_ + q32]      = f2bf(acc0[r] * ir);
            O[row * D_ + h * HD_ + 32 + q32] = f2bf(acc1[r] * ir);
        }
        // all warps passed the loop's final barrier before any phase-B STAGE;
        // store-O touches no LDS, so no extra barrier needed here.
    }
#undef STAGE
}

// ---------------- launcher ----------------
extern "C" void kernel_launch(void* const* d_in, const int* in_sizes, int n_in,
                              void* d_out, int out_size, void* d_ws, size_t ws_size,
                              hipStream_t stream) {
    char* ws = (char*)d_ws;
    int* flag            = (int*)ws;
    unsigned short* Xb   = (unsigned short*)(ws + 256);
    unsigned short* W1t  = Xb + 8192L * 1024;    // [3072][1024]
    unsigned short* QKV  = W1t + 3072L * 1024;   // [8192][3072]
    unsigned short* W2t  = QKV + 8192L * 3072;   // [1024][1024]
    unsigned short* Ob   = W2t + 1024L * 1024;   // [8192][1024]
    unsigned short* Vt_g = Ob + 8192L * 1024;    // [64 bh][64 d][2048 s]
    float* b1            = (float*)(Vt_g + 64L * 64 * 2048);  // 3072
    float* b2            = b1 + 3072;                         // 1024

    sniff_kernel<<<1, 64, 0, stream>>>((const unsigned*)d_in[0], flag);

    cvt_bf16_kernel<<<4096, 256, 0, stream>>>(d_in[0], Xb, 8192L * 1024 / 8, flag);
    tcvt_kernel<<<dim3(96, 32), dim3(32, 8), 0, stream>>>(d_in[2], W1t, 1024, 3072, flag);
    tcvt_kernel<<<dim3(32, 32), dim3(32, 8), 0, stream>>>(d_in[4], W2t, 1024, 1024, flag);
    cvt_f32_kernel<<<12, 256, 0, stream>>>(d_in[3], b1, 3072, flag);
    cvt_f32_kernel<<<4, 256, 0, stream>>>(d_in[5], b2, 1024, flag);

    // QKV = X @ W_attn + b_attn  (bf16 out)
    gemm_bt_kernel<<<dim3(64, 24), 256, 0, stream>>>(Xb, W1t, b1, QKV, 8192, 3072, 1024, nullptr);

    // V -> Vt_g [bh][d][s]
    vtrans_kernel<<<dim3(32, 64), 512, 0, stream>>>(QKV, Vt_g);

    // causal flash attention (paired q-tiles: uniform 34 kv-tiles/block)
    attn_kernel<<<dim3(8, 16, 4), 256, 0, stream>>>(QKV, Vt_g, Ob);

    // out = O @ W_proj + b_proj  (dtype per sniffed flag)
    gemm_bt_kernel<<<dim3(64, 8), 256, 0, stream>>>(Ob, W2t, b2, d_out, 8192, 1024, 1024, flag);
}